// Round 12
// baseline (2558.763 us; speedup 1.0000x reference)
//
#include <hip/hip_runtime.h>
#include <hip/hip_bf16.h>

typedef __bf16 bf16;
typedef __bf16 bf16x8 __attribute__((ext_vector_type(8)));
typedef __bf16 bf16x4 __attribute__((ext_vector_type(4)));
typedef float f32x4 __attribute__((ext_vector_type(4)));
typedef float f32x16 __attribute__((ext_vector_type(16)));

#define T_SEQ 80
#define NB 128
#define NT 768
#define U 1024
#define U3 3072

// ws byte offsets
#define WT_OFF   0ull                  // 3*3072*1024*2 = 18874368
#define WXT_OFF  18874368ull           // 3072*128*2    = 786432
#define XG_OFF   19660800ull           // 80*128*128*2  = 2621440
#define GX1_OFF  22282240ull           // 80*3072*128*2 = 62914560
#define H0B_OFF  85196800ull           // 81 * 128*1024*2 = 21233664 (deep buffers)
#define H1B_OFF  106430464ull          // 21233664
#define CNT_OFF  127664128ull          // barrier counters (2048 B)
#define WS_NEED  127666176ull

#define HBUF_ELEMS 131072ull           // 128*1024 bf16 per h buffer

#define LDS_SX_OFF   147456                 // after 3*24*1024 bf16 weights
#define LDS_RED_OFF  (147456 + 4*64*24*2)   // after SxL[4][64][24] bf16 = 12288
#define LDS_BYTES    (LDS_RED_OFF + 64)     // = 159808 <= 163840

__device__ __forceinline__ float sigmoidf_(float x) { return 1.f / (1.f + __expf(-x)); }

__global__ void k_embed(const int* __restrict__ tok, const float* __restrict__ E,
                        bf16* __restrict__ Xg) {
  int idx = blockIdx.x * 256 + threadIdx.x;   // over 80*128*128, layout [t][b][k]
  int k = idx & 127;
  int bt = idx >> 7;
  int b = bt & 127;
  int t = bt >> 7;
  float v = 0.f;
  if (k < 100) v = E[(size_t)tok[b * 80 + t] * 100 + k];
  Xg[idx] = (bf16)v;
}

__global__ void k_trans(const float* __restrict__ Wh1, const float* __restrict__ Wx2,
                        const float* __restrict__ Wh2, bf16* __restrict__ WT) {
  __shared__ float tile[32][33];
  const float* src = (blockIdx.z == 0) ? Wh1 : (blockIdx.z == 1) ? Wx2 : Wh2;
  int cb = blockIdx.x * 32, kb = blockIdx.y * 32;
  int tx = threadIdx.x, ty = threadIdx.y;
  for (int i = ty; i < 32; i += 8) tile[i][tx] = src[(size_t)(kb + i) * U3 + cb + tx];
  __syncthreads();
  bf16* dst = WT + (size_t)blockIdx.z * U3 * U;  // [col][k] bf16
  for (int i = ty; i < 32; i += 8) dst[(size_t)(cb + i) * U + kb + tx] = (bf16)tile[tx][i];
}

__global__ void k_wxt(const float* __restrict__ Wx1, bf16* __restrict__ WXT) {
  __shared__ float tile[32][33];
  int cb = blockIdx.x * 32, kb = blockIdx.y * 32;
  int tx = threadIdx.x, ty = threadIdx.y;
  for (int i = ty; i < 32; i += 8) {
    int k = kb + i;
    tile[i][tx] = (k < 100) ? Wx1[(size_t)k * U3 + cb + tx] : 0.f;
  }
  __syncthreads();
  for (int i = ty; i < 32; i += 8) WXT[(size_t)(cb + i) * 128 + kb + tx] = (bf16)tile[tx][i];
}

// GX1[t][col][b] = (x_t @ Wx1 + bx1), bf16, col-major over batch
__global__ __launch_bounds__(256) void k_gx1(const bf16* __restrict__ Xg,
                                             const bf16* __restrict__ WXT,
                                             const float* __restrict__ bx1,
                                             bf16* __restrict__ GX1) {
  int mb = blockIdx.x * 64, nb = blockIdx.y * 64;
  int w = threadIdx.x >> 6, l = threadIdx.x & 63;
  int lr = l & 15, lq = l >> 4;
  int rowA = mb + w * 16 + lr;                 // m = t*128 + b
  int tA = rowA >> 7, bA = rowA & 127;
  const bf16* aptr = Xg + ((size_t)tA * 128 + bA) * 128 + lq * 8;
  f32x4 acc[4] = {};
  #pragma unroll
  for (int ks = 0; ks < 4; ++ks) {
    bf16x8 a = *(const bf16x8*)(aptr + ks * 32);
    #pragma unroll
    for (int nt = 0; nt < 4; ++nt) {
      int col = nb + nt * 16 + lr;
      bf16x8 b = *(const bf16x8*)(WXT + (size_t)col * 128 + ks * 32 + lq * 8);
      acc[nt] = __builtin_amdgcn_mfma_f32_16x16x32_bf16(a, b, acc[nt], 0, 0, 0);
    }
  }
  int m0 = mb + w * 16 + lq * 4;
  int t0 = m0 >> 7, b0 = m0 & 127;
  #pragma unroll
  for (int nt = 0; nt < 4; ++nt) {
    int col = nb + nt * 16 + lr;
    float bias = bx1[col];
    bf16x4 o;
    #pragma unroll
    for (int j = 0; j < 4; ++j) o[j] = (bf16)(acc[nt][j] + bias);
    *(bf16x4*)(GX1 + ((size_t)t0 * U3 + col) * 128 + b0) = o;
  }
}

// B-fragment for 32x32x16: lane supplies col (l&31 -> slot scol), k=16s + hi*8..+8.
// Slot data is 4-bit XOR-swizzled at 16B-granule level: granule m stored at m^(scol&15).
__device__ __forceinline__ bf16x8 ldsw32(const bf16* Wlds, int mat, int scol, int m) {
  return *(const bf16x8*)(Wlds + (((mat * 24 + scol) << 10) + ((m ^ (scol & 15)) << 3)));
}

// Packed-pair h store: lanes c (even) and c+1 hold adjacent columns, same row.
// Agent-scope relaxed atomic store -> data lands at the coherence point (IF).
__device__ __forceinline__ void st_pair(bf16* dst_even, int c, float h) {
  bf16 hb16 = (bf16)h;
  unsigned hb = (unsigned)__builtin_bit_cast(unsigned short, hb16);
  unsigned pb = (unsigned)__shfl_xor((int)hb, 1) & 0xffffu;
  if (!(c & 1)) {
    unsigned v = hb | (pb << 16);
    __hip_atomic_store((unsigned*)dst_even, v, __ATOMIC_RELAXED, __HIP_MEMORY_SCOPE_AGENT);
  }
}

// Fence-free tree barrier (measured ~1.67 us/barrier at 128 blocks).
__device__ void gridbar(int* cnt, int i) {
  __syncthreads();
  if (threadIdx.x == 0) {
    int* gc   = cnt + (blockIdx.x & 7) * 32;   // 128B apart
    int* root = cnt + 256;
    int* go   = cnt + 288;
    int old = __hip_atomic_fetch_add(gc, 1, __ATOMIC_RELAXED, __HIP_MEMORY_SCOPE_AGENT);
    if (old == 16 * (i + 1) - 1) {             // group leader this iteration
      int r = __hip_atomic_fetch_add(root, 1, __ATOMIC_RELAXED, __HIP_MEMORY_SCOPE_AGENT);
      if (r == 8 * (i + 1) - 1)
        __hip_atomic_store(go, i + 1, __ATOMIC_RELAXED, __HIP_MEMORY_SCOPE_AGENT);
    }
    while (__hip_atomic_load(go, __ATOMIC_RELAXED, __HIP_MEMORY_SCOPE_AGENT) < i + 1)
      __builtin_amdgcn_s_sleep(4);
  }
  __syncthreads();
}

// NT=768, 12 waves, 3/SIMD, 32x32x16 MFMA, one wave per (row-tile, matrix):
//   waves 0-3:  gh1 = H0[i-1] @ Wh1 (full K) + h0 update (owns hm for H0 rows 32w)
//   waves 4-7:  gx2 = H0[i-1] @ Wx2 (full K) -> SxL deposit
//   waves 8-11: gh2 = H1[i-2] @ Wh2 (full K) + h1 update (owns hm for H1 rows 32(w-8))
// B-tile cols: 0-7=z, 8-15=r, 16-23=n, 24-31 mirror z (output ignored).
__global__ __launch_bounds__(NT, 3) void k_main(
    const bf16* __restrict__ WT, const bf16* __restrict__ GX1,
    bf16* __restrict__ h0b, bf16* __restrict__ h1b, int* __restrict__ cnt,
    const float* __restrict__ bh1, const float* __restrict__ bx2,
    const float* __restrict__ bh2, const float* __restrict__ Wf,
    const float* __restrict__ bfp, float* __restrict__ out) {
  extern __shared__ char lds[];
  bf16* Wlds = (bf16*)lds;
  bf16* SxL  = (bf16*)(lds + LDS_SX_OFF);     // [4 tiles][64 lanes][24] gx2 deposit
  float* red = (float*)(lds + LDS_RED_OFF);

  const int tid = threadIdx.x;
  const int w = tid >> 6, l = tid & 63;
  const int c = l & 31, hi = l >> 5;
  const int c0 = blockIdx.x * 8;              // this block's h-column base
  const int scol = (c < 24) ? c : (c - 24);

  // global column this lane's B-slot corresponds to (mirror lanes -> z again)
  int col_g;
  if (c < 8)       col_g = c0 + c;
  else if (c < 16) col_g = U + c0 + (c - 8);
  else if (c < 24) col_g = 2 * U + c0 + (c - 16);
  else             col_g = c0 + (c - 24);

  // ---- stage 3x24 weight columns into LDS (bf16, k-contiguous, XOR-swizzled) ----
  for (int u = tid; u < 9216; u += NT) {      // 72 slots * 128 granules
    int chunk = u & 127;
    int s72 = u >> 7;
    int mat = s72 / 24, s = s72 - mat * 24;
    int gcol = c0 + (s & 7) + ((s >> 3) << 10);   // s<8:z  8..15:r(+1024)  16..23:n(+2048)
    bf16x8 v = *(const bf16x8*)(WT + ((size_t)mat * U3 + gcol) * U + chunk * 8);
    *(bf16x8*)(Wlds + ((size_t)s72 << 10) + ((chunk ^ (s & 15)) << 3)) = v;
  }
  __syncthreads();

  // ---- per-lane biases (constant across iters) ----
  const float b1c  = bh1[col_g];
  const float bx2c = bx2[col_g];
  const float bh2c = bh2[col_g];

  float hm[16];                               // fp32 master state (cols c<8 lanes only)
  #pragma unroll
  for (int q = 0; q < 16; ++q) hm[q] = 0.f;

  for (int i = 0; i <= T_SEQ; ++i) {
    // deep buffers: iter i reads h0b[i], h1b[i-1]; writes h0b[i+1], h1b[i].
    const bf16* h0r = h0b + (size_t)i * HBUF_ELEMS;
    const bf16* h1r = h1b + (size_t)(i > 0 ? i - 1 : 0) * HBUF_ELEMS;
    bf16* h0w = h0b + (size_t)(i + 1) * HBUF_ELEMS;
    bf16* h1w = h1b + (size_t)i * HBUF_ELEMS;

    f32x16 acc3 = {};                         // gh2 acc lives across the mid-sync

    if (w < 4) {
      // ===== gh1 waves: rows 32w, A=H0[i-1], B=Wh1, full K; then h0 update =====
      f32x16 acc1 = {};
      const bf16* A0 = h0r + (size_t)(w * 32 + c) * U + hi * 8;
      #pragma unroll 8
      for (int s = 0; s < 64; ++s) {
        bf16x8 A = *(const bf16x8*)(A0 + s * 16);
        bf16x8 B1 = ldsw32(Wlds, 0, scol, 2 * s + hi);
        acc1 = __builtin_amdgcn_mfma_f32_32x32x16_bf16(A, B1, acc1, 0, 0, 0);
      }
      // h0 update: H0[i] = GRU1(H0[i-1], x[i])
      if (i < T_SEQ) {
        float g[16], p[16], q[16];
        const bf16* gx = GX1 + (size_t)i * U3 * 128 + (size_t)col_g * 128 + w * 32 + 4 * hi;
        #pragma unroll
        for (int m = 0; m < 4; ++m) {
          bf16x4 t = *(const bf16x4*)(gx + 8 * m);
          #pragma unroll
          for (int j = 0; j < 4; ++j) g[4 * m + j] = (float)t[j];
        }
        #pragma unroll
        for (int r = 0; r < 16; ++r) { p[r] = acc1[r] + b1c; q[r] = p[r] + g[r]; }
        float rr[16], gn[16], pn[16];
        #pragma unroll
        for (int r = 0; r < 16; ++r) {
          rr[r] = __shfl_xor(q[r], 8);        // r-gate preact (col c+8)
          gn[r] = __shfl_xor(g[r], 16);       // gx1 n-part   (col c+16)
          pn[r] = __shfl_xor(p[r], 16);       // gh1 n-part   (col c+16)
        }
        if (c < 8) {
          #pragma unroll
          for (int r = 0; r < 16; ++r) {
            float z  = sigmoidf_(q[r]);
            float rv = sigmoidf_(rr[r]);
            float nn = tanhf(gn[r] + rv * pn[r]);
            float h  = z * hm[r] + (1.f - z) * nn;
            hm[r] = h;
            int row = w * 32 + (r & 3) + 8 * (r >> 2) + 4 * hi;
            st_pair(h0w + (size_t)row * U + c0 + (c & ~1), c, h);
          }
        }
      }
    } else if (w < 8) {
      // ===== gx2 waves: rows 32(w-4), A=H0[i-1], B=Wx2, full K; deposit to SxL =====
      const int wt = w - 4;
      f32x16 acc2 = {};
      const bf16* A0 = h0r + (size_t)(wt * 32 + c) * U + hi * 8;
      #pragma unroll 8
      for (int s = 0; s < 64; ++s) {
        bf16x8 A = *(const bf16x8*)(A0 + s * 16);
        bf16x8 B2 = ldsw32(Wlds, 1, scol, 2 * s + hi);
        acc2 = __builtin_amdgcn_mfma_f32_32x32x16_bf16(A, B2, acc2, 0, 0, 0);
      }
      {
        bf16* sx = SxL + (size_t)(wt * 64 + l) * 24;
        #pragma unroll
        for (int m = 0; m < 4; ++m) {
          bf16x4 t;
          #pragma unroll
          for (int j = 0; j < 4; ++j) t[j] = (bf16)acc2[4 * m + j];
          *(bf16x4*)(sx + 4 * m) = t;
        }
      }
    } else if (i > 0) {
      // ===== gh2 waves: rows 32(w-8), A=H1[i-2], B=Wh2, full K =====
      const int wt = w - 8;
      const bf16* A1 = h1r + (size_t)(wt * 32 + c) * U + hi * 8;
      #pragma unroll 8
      for (int s = 0; s < 64; ++s) {
        bf16x8 A = *(const bf16x8*)(A1 + s * 16);
        bf16x8 B3 = ldsw32(Wlds, 2, scol, 2 * s + hi);
        acc3 = __builtin_amdgcn_mfma_f32_32x32x16_bf16(A, B3, acc3, 0, 0, 0);
      }
    }
    __syncthreads();   // SxL (gx2) visible to gh2 waves
    if (w >= 8 && i > 0) {
      // h1 update: H1 = GRU2(H1, H0[i-1])
      const int wt = w - 8;
      float p2[16], p3[16], q[16];
      {
        const bf16* sx = SxL + (size_t)(wt * 64 + l) * 24;
        #pragma unroll
        for (int m = 0; m < 4; ++m) {
          bf16x4 t = *(const bf16x4*)(sx + 4 * m);
          #pragma unroll
          for (int j = 0; j < 4; ++j) p2[4 * m + j] = (float)t[j];
        }
      }
      #pragma unroll
      for (int r = 0; r < 16; ++r) {
        p2[r] = p2[r] + bx2c;                 // gx2 + bx2
        p3[r] = acc3[r] + bh2c;               // gh2 + bh2
        q[r]  = p2[r] + p3[r];
      }
      float rr[16], xn[16], hn[16];
      #pragma unroll
      for (int r = 0; r < 16; ++r) {
        rr[r] = __shfl_xor(q[r], 8);
        xn[r] = __shfl_xor(p2[r], 16);
        hn[r] = __shfl_xor(p3[r], 16);
      }
      if (c < 8) {
        #pragma unroll
        for (int r = 0; r < 16; ++r) {
          float z  = sigmoidf_(q[r]);
          float rv = sigmoidf_(rr[r]);
          float nn = tanhf(xn[r] + rv * hn[r]);
          float h  = z * hm[r] + (1.f - z) * nn;
          hm[r] = h;
          int row = wt * 32 + (r & 3) + 8 * (r >> 2) + 4 * hi;
          st_pair(h1w + (size_t)row * U + c0 + (c & ~1), c, h);
        }
      }
    }
    gridbar(cnt, i);
  }

  // ---- final dense head: out[b] = sigmoid(H1[79] . Wf + bf), block b ----
  {
    const bf16* h1f = h1b + (size_t)T_SEQ * HBUF_ELEMS + (size_t)blockIdx.x * U;
    float part = 0.f;
    if (tid < 256) {
      int k0 = tid * 4;
      bf16x4 hv = *(const bf16x4*)(h1f + k0);
      #pragma unroll
      for (int j = 0; j < 4; ++j) part += (float)hv[j] * Wf[k0 + j];
    }
    #pragma unroll
    for (int off = 32; off > 0; off >>= 1) part += __shfl_down(part, off);
    if (l == 0) red[w] = part;
    __syncthreads();
    if (tid == 0) {
      float s = bfp[0];
      #pragma unroll
      for (int q = 0; q < 12; ++q) s += red[q];
      out[blockIdx.x] = sigmoidf_(s);
    }
  }
}

extern "C" void kernel_launch(void* const* d_in, const int* in_sizes, int n_in,
                              void* d_out, int out_size, void* d_ws, size_t ws_size,
                              hipStream_t stream) {
  if (ws_size < WS_NEED) return;  // workspace insufficient -> deliberate clean fail
  const int*   tok = (const int*)d_in[0];
  const float* E   = (const float*)d_in[1];
  const float* Wx1 = (const float*)d_in[2];
  const float* Wh1 = (const float*)d_in[3];
  const float* bx1 = (const float*)d_in[4];
  const float* bh1 = (const float*)d_in[5];
  const float* Wx2 = (const float*)d_in[6];
  const float* Wh2 = (const float*)d_in[7];
  const float* bx2 = (const float*)d_in[8];
  const float* bh2 = (const float*)d_in[9];
  const float* Wf  = (const float*)d_in[10];
  const float* bfp = (const float*)d_in[11];
  char* ws = (char*)d_ws;
  bf16* WT   = (bf16*)(ws + WT_OFF);
  bf16* WXT  = (bf16*)(ws + WXT_OFF);
  bf16* Xg   = (bf16*)(ws + XG_OFF);
  bf16* GX1  = (bf16*)(ws + GX1_OFF);
  bf16* h0b  = (bf16*)(ws + H0B_OFF);
  bf16* h1b  = (bf16*)(ws + H1B_OFF);
  int*  cnt  = (int*)(ws + CNT_OFF);

  // zero only what's read-before-write: h0b[0], h1b[0], counters
  hipMemsetAsync(ws + H0B_OFF, 0, 262144, stream);
  hipMemsetAsync(ws + H1B_OFF, 0, 262144, stream);
  hipMemsetAsync(ws + CNT_OFF, 0, 2048, stream);
  k_embed<<<dim3(5120), dim3(256), 0, stream>>>(tok, E, Xg);
  k_trans<<<dim3(96, 32, 3), dim3(32, 8), 0, stream>>>(Wh1, Wx2, Wh2, WT);
  k_wxt<<<dim3(96, 4), dim3(32, 8), 0, stream>>>(Wx1, WXT);
  k_gx1<<<dim3(160, 48), dim3(256), 0, stream>>>(Xg, WXT, bx1, GX1);
  hipFuncSetAttribute((const void*)k_main, hipFuncAttributeMaxDynamicSharedMemorySize, LDS_BYTES);
  k_main<<<dim3(NB), dim3(NT), LDS_BYTES, stream>>>(WT, GX1, h0b, h1b, cnt,
                                                    bh1, bx2, bh2, Wf, bfp, (float*)d_out);
}

// Round 13
// 2050.682 us; speedup vs baseline: 1.2478x; 1.2478x over previous
//
#include <hip/hip_runtime.h>
#include <hip/hip_bf16.h>

typedef __bf16 bf16;
typedef __bf16 bf16x8 __attribute__((ext_vector_type(8)));
typedef __bf16 bf16x4 __attribute__((ext_vector_type(4)));
typedef float f32x4 __attribute__((ext_vector_type(4)));
typedef float f32x16 __attribute__((ext_vector_type(16)));

#define T_SEQ 80
#define NB 128
#define NT 1024
#define U 1024
#define U3 3072

// ws byte offsets
#define WT_OFF   0ull                  // 3*3072*1024*2 = 18874368
#define WXT_OFF  18874368ull           // 3072*128*2    = 786432
#define XG_OFF   19660800ull           // 80*128*128*2  = 2621440 (dead after k_gx1 -> P2 scratch)
#define GX1_OFF  22282240ull           // 80*3072*128*2 = 62914560
#define H0B_OFF  85196800ull           // 81 * 128*1024*2 = 21233664 (deep buffers)
#define H1B_OFF  106430464ull          // 21233664
#define CNT_OFF  127664128ull          // barrier counters (2048 B)
#define WS_NEED  127666176ull

#define HBUF_ELEMS 131072ull           // 128*1024 bf16 per h buffer

#define LDS_P1_OFF  147456                 // after 3*24*1024 bf16 weights; P1[4][64][16] bf16
#define LDS_P3_OFF  (147456 + 8192)        // P3[4][64][16] bf16
#define LDS_BYTES   163840                 // exactly the 160 KiB pool

__device__ __forceinline__ float sigmoidf_(float x) { return 1.f / (1.f + __expf(-x)); }

__global__ void k_embed(const int* __restrict__ tok, const float* __restrict__ E,
                        bf16* __restrict__ Xg) {
  int idx = blockIdx.x * 256 + threadIdx.x;   // over 80*128*128, layout [t][b][k]
  int k = idx & 127;
  int bt = idx >> 7;
  int b = bt & 127;
  int t = bt >> 7;
  float v = 0.f;
  if (k < 100) v = E[(size_t)tok[b * 80 + t] * 100 + k];
  Xg[idx] = (bf16)v;
}

__global__ void k_trans(const float* __restrict__ Wh1, const float* __restrict__ Wx2,
                        const float* __restrict__ Wh2, bf16* __restrict__ WT) {
  __shared__ float tile[32][33];
  const float* src = (blockIdx.z == 0) ? Wh1 : (blockIdx.z == 1) ? Wx2 : Wh2;
  int cb = blockIdx.x * 32, kb = blockIdx.y * 32;
  int tx = threadIdx.x, ty = threadIdx.y;
  for (int i = ty; i < 32; i += 8) tile[i][tx] = src[(size_t)(kb + i) * U3 + cb + tx];
  __syncthreads();
  bf16* dst = WT + (size_t)blockIdx.z * U3 * U;  // [col][k] bf16
  for (int i = ty; i < 32; i += 8) dst[(size_t)(cb + i) * U + kb + tx] = (bf16)tile[tx][i];
}

__global__ void k_wxt(const float* __restrict__ Wx1, bf16* __restrict__ WXT) {
  __shared__ float tile[32][33];
  int cb = blockIdx.x * 32, kb = blockIdx.y * 32;
  int tx = threadIdx.x, ty = threadIdx.y;
  for (int i = ty; i < 32; i += 8) {
    int k = kb + i;
    tile[i][tx] = (k < 100) ? Wx1[(size_t)k * U3 + cb + tx] : 0.f;
  }
  __syncthreads();
  for (int i = ty; i < 32; i += 8) WXT[(size_t)(cb + i) * 128 + kb + tx] = (bf16)tile[tx][i];
}

// GX1[t][col][b] = (x_t @ Wx1 + bx1), bf16, col-major over batch
__global__ __launch_bounds__(256) void k_gx1(const bf16* __restrict__ Xg,
                                             const bf16* __restrict__ WXT,
                                             const float* __restrict__ bx1,
                                             bf16* __restrict__ GX1) {
  int mb = blockIdx.x * 64, nb = blockIdx.y * 64;
  int w = threadIdx.x >> 6, l = threadIdx.x & 63;
  int lr = l & 15, lq = l >> 4;
  int rowA = mb + w * 16 + lr;                 // m = t*128 + b
  int tA = rowA >> 7, bA = rowA & 127;
  const bf16* aptr = Xg + ((size_t)tA * 128 + bA) * 128 + lq * 8;
  f32x4 acc[4] = {};
  #pragma unroll
  for (int ks = 0; ks < 4; ++ks) {
    bf16x8 a = *(const bf16x8*)(aptr + ks * 32);
    #pragma unroll
    for (int nt = 0; nt < 4; ++nt) {
      int col = nb + nt * 16 + lr;
      bf16x8 b = *(const bf16x8*)(WXT + (size_t)col * 128 + ks * 32 + lq * 8);
      acc[nt] = __builtin_amdgcn_mfma_f32_16x16x32_bf16(a, b, acc[nt], 0, 0, 0);
    }
  }
  int m0 = mb + w * 16 + lq * 4;
  int t0 = m0 >> 7, b0 = m0 & 127;
  #pragma unroll
  for (int nt = 0; nt < 4; ++nt) {
    int col = nb + nt * 16 + lr;
    float bias = bx1[col];
    bf16x4 o;
    #pragma unroll
    for (int j = 0; j < 4; ++j) o[j] = (bf16)(acc[nt][j] + bias);
    *(bf16x4*)(GX1 + ((size_t)t0 * U3 + col) * 128 + b0) = o;
  }
}

// B-fragment for 32x32x16: lane supplies col (slot scol), granule m (16B index in k).
// Slot data 4-bit XOR-swizzled at 16B granularity (r11/r12 validated: conflicts 26x down).
__device__ __forceinline__ bf16x8 ldsw32(const bf16* Wlds, int mat, int scol, int m) {
  return *(const bf16x8*)(Wlds + (((mat * 24 + scol) << 10) + ((m ^ (scol & 15)) << 3)));
}

// Packed-pair h store: lanes c (even) and c+1 hold adjacent columns, same row.
// Agent-scope relaxed atomic store -> data lands at the coherence point (IF).
__device__ __forceinline__ void st_pair(bf16* dst_even, int c, float h) {
  bf16 hb16 = (bf16)h;
  unsigned hb = (unsigned)__builtin_bit_cast(unsigned short, hb16);
  unsigned pb = (unsigned)__shfl_xor((int)hb, 1) & 0xffffu;
  if (!(c & 1)) {
    unsigned v = hb | (pb << 16);
    __hip_atomic_store((unsigned*)dst_even, v, __ATOMIC_RELAXED, __HIP_MEMORY_SCOPE_AGENT);
  }
}

// Fence-free tree barrier (measured ~1.67 us/barrier at 128 blocks).
__device__ void gridbar(int* cnt, int i) {
  __syncthreads();
  if (threadIdx.x == 0) {
    int* gc   = cnt + (blockIdx.x & 7) * 32;   // 128B apart
    int* root = cnt + 256;
    int* go   = cnt + 288;
    int old = __hip_atomic_fetch_add(gc, 1, __ATOMIC_RELAXED, __HIP_MEMORY_SCOPE_AGENT);
    if (old == 16 * (i + 1) - 1) {             // group leader this iteration
      int r = __hip_atomic_fetch_add(root, 1, __ATOMIC_RELAXED, __HIP_MEMORY_SCOPE_AGENT);
      if (r == 8 * (i + 1) - 1)
        __hip_atomic_store(go, i + 1, __ATOMIC_RELAXED, __HIP_MEMORY_SCOPE_AGENT);
    }
    while (__hip_atomic_load(go, __ATOMIC_RELAXED, __HIP_MEMORY_SCOPE_AGENT) < i + 1)
      __builtin_amdgcn_s_sleep(4);
  }
  __syncthreads();
}

// NT=1024, 16 waves (4/SIMD), 32x32x16 MFMA, K-SPLIT WAVE PAIRS:
//   waves 0-7  = 4 h0-pairs: pair p rows 32p; each half-wave does half-K of
//                gh1 AND gx2 (shared A). 32-step A chains (= r9 length).
//   waves 8-15 = 4 h1-pairs: pair p rows 32p; half-K of gh2.
//   half-1 deposits partials (bf16): gh1->P1(LDS), gh2->P3(LDS);
//   gx2 both halves -> P2 (block-private global scratch, L2-resident).
//   half-0 waves combine post-sync and do the gate updates.
__global__ __launch_bounds__(NT, 4) void k_main(
    const bf16* __restrict__ WT, const bf16* __restrict__ GX1,
    bf16* __restrict__ h0b, bf16* __restrict__ h1b, int* __restrict__ cnt,
    bf16* __restrict__ P2g,
    const float* __restrict__ bh1, const float* __restrict__ bx2,
    const float* __restrict__ bh2, const float* __restrict__ Wf,
    const float* __restrict__ bfp, float* __restrict__ out) {
  extern __shared__ char lds[];
  bf16* Wlds = (bf16*)lds;
  bf16* P1 = (bf16*)(lds + LDS_P1_OFF);       // [4][64][16] gh1 half-1 partial
  bf16* P3 = (bf16*)(lds + LDS_P3_OFF);       // [4][64][16] gh2 half-1 partial

  const int tid = threadIdx.x;
  const int w = tid >> 6, l = tid & 63;
  const int c = l & 31, hi = l >> 5;
  const int pr = (w >> 1) & 3;                // pair index within role
  const int half = w & 1;
  const int c0 = blockIdx.x * 8;              // this block's h-column base
  const int scol = (c < 24) ? c : (c - 24);

  // global column this lane's B-slot corresponds to (mirror lanes -> z again)
  int col_g;
  if (c < 8)       col_g = c0 + c;
  else if (c < 16) col_g = U + c0 + (c - 8);
  else if (c < 24) col_g = 2 * U + c0 + (c - 16);
  else             col_g = c0 + (c - 24);

  // block-private P2 scratch: [4 pairs][2 halves][64 lanes][16] bf16 = 16KB
  bf16* P2blk = P2g + (size_t)blockIdx.x * 8192;

  // ---- stage 3x24 weight columns into LDS (bf16, k-contiguous, XOR-swizzled) ----
  for (int u = tid; u < 9216; u += NT) {      // 72 slots * 128 granules
    int chunk = u & 127;
    int s72 = u >> 7;
    int mat = s72 / 24, s = s72 - mat * 24;
    int gcol = c0 + (s & 7) + ((s >> 3) << 10);   // s<8:z  8..15:r(+1024)  16..23:n(+2048)
    bf16x8 v = *(const bf16x8*)(WT + ((size_t)mat * U3 + gcol) * U + chunk * 8);
    *(bf16x8*)(Wlds + ((size_t)s72 << 10) + ((chunk ^ (s & 15)) << 3)) = v;
  }
  __syncthreads();

  // ---- per-lane biases (constant across iters) ----
  const float b1c  = bh1[col_g];
  const float bx2c = bx2[col_g];
  const float bh2c = bh2[col_g];

  float hm[16];                               // fp32 master state (half-0 waves, c<8 lanes)
  #pragma unroll
  for (int q = 0; q < 16; ++q) hm[q] = 0.f;

  for (int i = 0; i <= T_SEQ; ++i) {
    // deep buffers: iter i reads h0b[i], h1b[i-1]; writes h0b[i+1], h1b[i].
    const bf16* h0r = h0b + (size_t)i * HBUF_ELEMS;
    const bf16* h1r = h1b + (size_t)(i > 0 ? i - 1 : 0) * HBUF_ELEMS;
    bf16* h0w = h0b + (size_t)(i + 1) * HBUF_ELEMS;
    bf16* h1w = h1b + (size_t)i * HBUF_ELEMS;

    f32x16 acc1 = {}, acc3 = {};              // survive to post-sync update

    if (w < 8) {
      // ===== h0-pair wave: half-K of gh1 + gx2, rows 32*pr, shared A =====
      f32x16 acc2 = {};
      const bf16* A0 = h0r + (size_t)(pr * 32 + c) * U + half * 512 + hi * 8;
      #pragma unroll 8
      for (int s = 0; s < 32; ++s) {
        bf16x8 A = *(const bf16x8*)(A0 + s * 16);
        int m = 2 * (s + 32 * half) + hi;
        bf16x8 B1 = ldsw32(Wlds, 0, scol, m);
        bf16x8 B2 = ldsw32(Wlds, 1, scol, m);
        acc1 = __builtin_amdgcn_mfma_f32_32x32x16_bf16(A, B1, acc1, 0, 0, 0);
        acc2 = __builtin_amdgcn_mfma_f32_32x32x16_bf16(A, B2, acc2, 0, 0, 0);
      }
      // gx2 partial -> block-private L2 scratch (both halves)
      {
        bf16* dst = P2blk + ((size_t)(pr * 2 + half) * 64 + l) * 16;
        #pragma unroll
        for (int m = 0; m < 4; ++m) {
          bf16x4 t;
          #pragma unroll
          for (int j = 0; j < 4; ++j) t[j] = (bf16)acc2[4 * m + j];
          *(bf16x4*)(dst + 4 * m) = t;
        }
      }
      // gh1 partial (half-1 only) -> LDS
      if (half) {
        bf16* dst = P1 + ((size_t)pr * 64 + l) * 16;
        #pragma unroll
        for (int m = 0; m < 4; ++m) {
          bf16x4 t;
          #pragma unroll
          for (int j = 0; j < 4; ++j) t[j] = (bf16)acc1[4 * m + j];
          *(bf16x4*)(dst + 4 * m) = t;
        }
      }
    } else if (i > 0) {
      // ===== h1-pair wave: half-K of gh2, rows 32*pr =====
      const bf16* A1 = h1r + (size_t)(pr * 32 + c) * U + half * 512 + hi * 8;
      #pragma unroll 8
      for (int s = 0; s < 32; ++s) {
        bf16x8 A = *(const bf16x8*)(A1 + s * 16);
        int m = 2 * (s + 32 * half) + hi;
        bf16x8 B3 = ldsw32(Wlds, 2, scol, m);
        acc3 = __builtin_amdgcn_mfma_f32_32x32x16_bf16(A, B3, acc3, 0, 0, 0);
      }
      if (half) {
        bf16* dst = P3 + ((size_t)pr * 64 + l) * 16;
        #pragma unroll
        for (int m = 0; m < 4; ++m) {
          bf16x4 t;
          #pragma unroll
          for (int j = 0; j < 4; ++j) t[j] = (bf16)acc3[4 * m + j];
          *(bf16x4*)(dst + 4 * m) = t;
        }
      }
    }
    __syncthreads();   // partials visible (LDS + block-local global via L1)

    if (w < 8 && !half && i < T_SEQ) {
      // ===== h0 update (half-0 of h0-pairs): combine gh1 halves, gates =====
      float a1t[16], g[16], p[16], q[16];
      {
        const bf16* src = P1 + ((size_t)pr * 64 + l) * 16;
        #pragma unroll
        for (int m = 0; m < 4; ++m) {
          bf16x4 t = *(const bf16x4*)(src + 4 * m);
          #pragma unroll
          for (int j = 0; j < 4; ++j) a1t[4 * m + j] = acc1[4 * m + j] + (float)t[j];
        }
      }
      const bf16* gx = GX1 + (size_t)i * U3 * 128 + (size_t)col_g * 128 + pr * 32 + 4 * hi;
      #pragma unroll
      for (int m = 0; m < 4; ++m) {
        bf16x4 t = *(const bf16x4*)(gx + 8 * m);
        #pragma unroll
        for (int j = 0; j < 4; ++j) g[4 * m + j] = (float)t[j];
      }
      #pragma unroll
      for (int r = 0; r < 16; ++r) { p[r] = a1t[r] + b1c; q[r] = p[r] + g[r]; }
      float rr[16], gn[16], pn[16];
      #pragma unroll
      for (int r = 0; r < 16; ++r) {
        rr[r] = __shfl_xor(q[r], 8);          // r-gate preact (col c+8)
        gn[r] = __shfl_xor(g[r], 16);         // gx1 n-part   (col c+16)
        pn[r] = __shfl_xor(p[r], 16);         // gh1 n-part   (col c+16)
      }
      if (c < 8) {
        #pragma unroll
        for (int r = 0; r < 16; ++r) {
          float z  = sigmoidf_(q[r]);
          float rv = sigmoidf_(rr[r]);
          float nn = tanhf(gn[r] + rv * pn[r]);
          float h  = z * hm[r] + (1.f - z) * nn;
          hm[r] = h;
          int row = pr * 32 + (r & 3) + 8 * (r >> 2) + 4 * hi;
          st_pair(h0w + (size_t)row * U + c0 + (c & ~1), c, h);
        }
      }
    }
    if (w >= 8 && !half && i > 0) {
      // ===== h1 update (half-0 of h1-pairs): combine gh2 + gx2 halves =====
      float p2v[16], p3v[16], q[16];
      {
        const bf16* s0 = P2blk + ((size_t)(pr * 2 + 0) * 64 + l) * 16;
        const bf16* s1 = P2blk + ((size_t)(pr * 2 + 1) * 64 + l) * 16;
        const bf16* s3 = P3 + ((size_t)pr * 64 + l) * 16;
        #pragma unroll
        for (int m = 0; m < 4; ++m) {
          bf16x4 t0 = *(const bf16x4*)(s0 + 4 * m);
          bf16x4 t1 = *(const bf16x4*)(s1 + 4 * m);
          bf16x4 t3 = *(const bf16x4*)(s3 + 4 * m);
          #pragma unroll
          for (int j = 0; j < 4; ++j) {
            p2v[4 * m + j] = (float)t0[j] + (float)t1[j] + bx2c;
            p3v[4 * m + j] = acc3[4 * m + j] + (float)t3[j] + bh2c;
          }
        }
      }
      #pragma unroll
      for (int r = 0; r < 16; ++r) q[r] = p2v[r] + p3v[r];
      float rr[16], xn[16], hn[16];
      #pragma unroll
      for (int r = 0; r < 16; ++r) {
        rr[r] = __shfl_xor(q[r], 8);
        xn[r] = __shfl_xor(p2v[r], 16);
        hn[r] = __shfl_xor(p3v[r], 16);
      }
      if (c < 8) {
        #pragma unroll
        for (int r = 0; r < 16; ++r) {
          float z  = sigmoidf_(q[r]);
          float rv = sigmoidf_(rr[r]);
          float nn = tanhf(xn[r] + rv * hn[r]);
          float h  = z * hm[r] + (1.f - z) * nn;
          hm[r] = h;
          int row = pr * 32 + (r & 3) + 8 * (r >> 2) + 4 * hi;
          st_pair(h1w + (size_t)row * U + c0 + (c & ~1), c, h);
        }
      }
    }
    gridbar(cnt, i);
  }

  // ---- final dense head: out[b] = sigmoid(H1[79] . Wf + bf), block b ----
  {
    float* red = (float*)(lds + LDS_P1_OFF);  // P1 region dead; reuse for reduction
    const bf16* h1f = h1b + (size_t)T_SEQ * HBUF_ELEMS + (size_t)blockIdx.x * U;
    float part = 0.f;
    if (tid < 256) {
      int k0 = tid * 4;
      bf16x4 hv = *(const bf16x4*)(h1f + k0);
      #pragma unroll
      for (int j = 0; j < 4; ++j) part += (float)hv[j] * Wf[k0 + j];
    }
    #pragma unroll
    for (int off = 32; off > 0; off >>= 1) part += __shfl_down(part, off);
    __syncthreads();
    if (l == 0) red[w] = part;
    __syncthreads();
    if (tid == 0) {
      float s = bfp[0];
      #pragma unroll
      for (int q = 0; q < 16; ++q) s += red[q];
      out[blockIdx.x] = sigmoidf_(s);
    }
  }
}

extern "C" void kernel_launch(void* const* d_in, const int* in_sizes, int n_in,
                              void* d_out, int out_size, void* d_ws, size_t ws_size,
                              hipStream_t stream) {
  if (ws_size < WS_NEED) return;  // workspace insufficient -> deliberate clean fail
  const int*   tok = (const int*)d_in[0];
  const float* E   = (const float*)d_in[1];
  const float* Wx1 = (const float*)d_in[2];
  const float* Wh1 = (const float*)d_in[3];
  const float* bx1 = (const float*)d_in[4];
  const float* bh1 = (const float*)d_in[5];
  const float* Wx2 = (const float*)d_in[6];
  const float* Wh2 = (const float*)d_in[7];
  const float* bx2 = (const float*)d_in[8];
  const float* bh2 = (const float*)d_in[9];
  const float* Wf  = (const float*)d_in[10];
  const float* bfp = (const float*)d_in[11];
  char* ws = (char*)d_ws;
  bf16* WT   = (bf16*)(ws + WT_OFF);
  bf16* WXT  = (bf16*)(ws + WXT_OFF);
  bf16* Xg   = (bf16*)(ws + XG_OFF);   // doubles as P2 scratch inside k_main
  bf16* GX1  = (bf16*)(ws + GX1_OFF);
  bf16* h0b  = (bf16*)(ws + H0B_OFF);
  bf16* h1b  = (bf16*)(ws + H1B_OFF);
  int*  cnt  = (int*)(ws + CNT_OFF);

  // zero only what's read-before-write: h0b[0], h1b[0], counters
  hipMemsetAsync(ws + H0B_OFF, 0, 262144, stream);
  hipMemsetAsync(ws + H1B_OFF, 0, 262144, stream);
  hipMemsetAsync(ws + CNT_OFF, 0, 2048, stream);
  k_embed<<<dim3(5120), dim3(256), 0, stream>>>(tok, E, Xg);
  k_trans<<<dim3(96, 32, 3), dim3(32, 8), 0, stream>>>(Wh1, Wx2, Wh2, WT);
  k_wxt<<<dim3(96, 4), dim3(32, 8), 0, stream>>>(Wx1, WXT);
  k_gx1<<<dim3(160, 48), dim3(256), 0, stream>>>(Xg, WXT, bx1, GX1);
  hipFuncSetAttribute((const void*)k_main, hipFuncAttributeMaxDynamicSharedMemorySize, LDS_BYTES);
  k_main<<<dim3(NB), dim3(NT), LDS_BYTES, stream>>>(WT, GX1, h0b, h1b, cnt, Xg,
                                                    bh1, bx2, bh2, Wf, bfp, (float*)d_out);
}

// Round 14
// 1542.934 us; speedup vs baseline: 1.6584x; 1.3291x over previous
//
#include <hip/hip_runtime.h>
#include <hip/hip_bf16.h>

typedef __bf16 bf16;
typedef __bf16 bf16x8 __attribute__((ext_vector_type(8)));
typedef __bf16 bf16x4 __attribute__((ext_vector_type(4)));
typedef float f32x4 __attribute__((ext_vector_type(4)));

#define T_SEQ 80
#define NB 128
#define NT 1024
#define U 1024
#define U3 3072

// ws byte offsets
#define WT_OFF   0ull                  // 3*3072*1024*2 = 18874368
#define WXT_OFF  18874368ull           // 3072*128*2    = 786432
#define XG_OFF   19660800ull           // 80*128*128*2  = 2621440
#define GX1_OFF  22282240ull           // 80*3072*128*2 = 62914560
#define H0B_OFF  85196800ull           // 81 * 128*1024*2 = 21233664 (deep buffers)
#define H1B_OFF  106430464ull          // 21233664
#define CNT_OFF  127664128ull          // barrier counters (2048 B)
#define WS_NEED  127666176ull

#define HBUF_ELEMS 131072ull           // 128*1024 bf16 per h buffer

#define LDS_SX2_OFF   147456                  // after 72*1024 bf16 weight slots
#define LDS_RED_OFF   (147456 + 24*132*4)     // after Sx2[24][132] f32
#define LDS_BYTES     (LDS_RED_OFF + 64)      // = 160192 <= 163840

__device__ __forceinline__ float sigmoidf_(float x) { return 1.f / (1.f + __expf(-x)); }

__global__ void k_embed(const int* __restrict__ tok, const float* __restrict__ E,
                        bf16* __restrict__ Xg) {
  int idx = blockIdx.x * 256 + threadIdx.x;   // over 80*128*128, layout [t][b][k]
  int k = idx & 127;
  int bt = idx >> 7;
  int b = bt & 127;
  int t = bt >> 7;
  float v = 0.f;
  if (k < 100) v = E[(size_t)tok[b * 80 + t] * 100 + k];
  Xg[idx] = (bf16)v;
}

__global__ void k_trans(const float* __restrict__ Wh1, const float* __restrict__ Wx2,
                        const float* __restrict__ Wh2, bf16* __restrict__ WT) {
  __shared__ float tile[32][33];
  const float* src = (blockIdx.z == 0) ? Wh1 : (blockIdx.z == 1) ? Wx2 : Wh2;
  int cb = blockIdx.x * 32, kb = blockIdx.y * 32;
  int tx = threadIdx.x, ty = threadIdx.y;
  for (int i = ty; i < 32; i += 8) tile[i][tx] = src[(size_t)(kb + i) * U3 + cb + tx];
  __syncthreads();
  bf16* dst = WT + (size_t)blockIdx.z * U3 * U;  // [col][k] bf16
  for (int i = ty; i < 32; i += 8) dst[(size_t)(cb + i) * U + kb + tx] = (bf16)tile[tx][i];
}

__global__ void k_wxt(const float* __restrict__ Wx1, bf16* __restrict__ WXT) {
  __shared__ float tile[32][33];
  int cb = blockIdx.x * 32, kb = blockIdx.y * 32;
  int tx = threadIdx.x, ty = threadIdx.y;
  for (int i = ty; i < 32; i += 8) {
    int k = kb + i;
    tile[i][tx] = (k < 100) ? Wx1[(size_t)k * U3 + cb + tx] : 0.f;
  }
  __syncthreads();
  for (int i = ty; i < 32; i += 8) WXT[(size_t)(cb + i) * 128 + kb + tx] = (bf16)tile[tx][i];
}

// GX1[t][col][b] = (x_t @ Wx1 + bx1), bf16, col-major over batch
__global__ __launch_bounds__(256) void k_gx1(const bf16* __restrict__ Xg,
                                             const bf16* __restrict__ WXT,
                                             const float* __restrict__ bx1,
                                             bf16* __restrict__ GX1) {
  int mb = blockIdx.x * 64, nb = blockIdx.y * 64;
  int w = threadIdx.x >> 6, l = threadIdx.x & 63;
  int lr = l & 15, lq = l >> 4;
  int rowA = mb + w * 16 + lr;                 // m = t*128 + b
  int tA = rowA >> 7, bA = rowA & 127;
  const bf16* aptr = Xg + ((size_t)tA * 128 + bA) * 128 + lq * 8;
  f32x4 acc[4] = {};
  #pragma unroll
  for (int ks = 0; ks < 4; ++ks) {
    bf16x8 a = *(const bf16x8*)(aptr + ks * 32);
    #pragma unroll
    for (int nt = 0; nt < 4; ++nt) {
      int col = nb + nt * 16 + lr;
      bf16x8 b = *(const bf16x8*)(WXT + (size_t)col * 128 + ks * 32 + lq * 8);
      acc[nt] = __builtin_amdgcn_mfma_f32_16x16x32_bf16(a, b, acc[nt], 0, 0, 0);
    }
  }
  int m0 = mb + w * 16 + lq * 4;
  int t0 = m0 >> 7, b0 = m0 & 127;
  #pragma unroll
  for (int nt = 0; nt < 4; ++nt) {
    int col = nb + nt * 16 + lr;
    float bias = bx1[col];
    bf16x4 o;
    #pragma unroll
    for (int j = 0; j < 4; ++j) o[j] = (bf16)(acc[nt][j] + bias);
    *(bf16x4*)(GX1 + ((size_t)t0 * U3 + col) * 128 + b0) = o;
  }
}

// Weight slot layout (72 slots x 1024 bf16, 16B-granule XOR-swizzled):
//   sid  0-15: Wh1 z(0-7) r(8-15)
//   sid 16-31: Wx2 z(0-7) r(8-15)
//   sid 32-55: Wh2 z(0-7) r(8-15) n(16-23)
//   sid 56-71: combined n: 56-63 = Wh1 n-cols, 64-71 = Wx2 n-cols
__device__ __forceinline__ bf16x8 ldsw(const bf16* Wlds, int sid, int k8) {
  return *(const bf16x8*)(Wlds + ((size_t)sid << 10) + ((k8 ^ (sid & 7) ^ (sid & 8)) << 3));
}

// Packed-pair h store: lanes lr (even) and lr+1 hold adjacent columns, same row.
// Agent-scope relaxed atomic store -> data lands at the coherence point (IF).
__device__ __forceinline__ void st_pair(bf16* dst_even, int lr, float h) {
  bf16 hb16 = (bf16)h;
  unsigned hb = (unsigned)__builtin_bit_cast(unsigned short, hb16);
  unsigned pb = (unsigned)__shfl_xor((int)hb, 1) & 0xffffu;
  if (!(lr & 1)) {
    unsigned v = hb | (pb << 16);
    __hip_atomic_store((unsigned*)dst_even, v, __ATOMIC_RELAXED, __HIP_MEMORY_SCOPE_AGENT);
  }
}

// Fence-free tree barrier (measured ~1.67 us/barrier at 128 blocks).
__device__ void gridbar(int* cnt, int i) {
  __syncthreads();
  if (threadIdx.x == 0) {
    int* gc   = cnt + (blockIdx.x & 7) * 32;   // 128B apart
    int* root = cnt + 256;
    int* go   = cnt + 288;
    int old = __hip_atomic_fetch_add(gc, 1, __ATOMIC_RELAXED, __HIP_MEMORY_SCOPE_AGENT);
    if (old == 16 * (i + 1) - 1) {             // group leader this iteration
      int r = __hip_atomic_fetch_add(root, 1, __ATOMIC_RELAXED, __HIP_MEMORY_SCOPE_AGENT);
      if (r == 8 * (i + 1) - 1)
        __hip_atomic_store(go, i + 1, __ATOMIC_RELAXED, __HIP_MEMORY_SCOPE_AGENT);
    }
    while (__hip_atomic_load(go, __ATOMIC_RELAXED, __HIP_MEMORY_SCOPE_AGENT) < i + 1)
      __builtin_amdgcn_s_sleep(4);
  }
  __syncthreads();
}

// NT=1024: waves 0-7 = h0 (gh1 + gx2 + combined-n, 16 rows each), waves 8-15 = h1.
// 4 waves/SIMD; 32-step shared-A chains (r9 skeleton, validated best).
__global__ __launch_bounds__(NT, 1) void k_main(
    const bf16* __restrict__ WT, const bf16* __restrict__ GX1,
    bf16* __restrict__ h0b, bf16* __restrict__ h1b, int* __restrict__ cnt,
    const float* __restrict__ bh1, const float* __restrict__ bx2,
    const float* __restrict__ bh2, const float* __restrict__ Wf,
    const float* __restrict__ bfp, float* __restrict__ out) {
  extern __shared__ char lds[];
  bf16* Wlds = (bf16*)lds;
  float* Sx2 = (float*)(lds + LDS_SX2_OFF);   // [24][132] f32: gx2 handoff
  float* red = (float*)(lds + LDS_RED_OFF);   // 16 floats

  const int tid = threadIdx.x;
  const int w = tid >> 6, l = tid & 63;
  const int lr = l & 15, lq = l >> 4;
  const int c0 = blockIdx.x * 8;              // this block's h-column base
  const int koff = (blockIdx.x & 7) * 4;      // per-block K-walk stagger

  // ---- stage 72 weight slots into LDS (bf16, k-contiguous, XOR-swizzled) ----
  for (int u = tid; u < 9216; u += NT) {      // 72 slots * 128 granules
    int chunk = u & 127;
    int sid = u >> 7;
    int mat, gcol;
    if (sid < 16)      { mat = 0; gcol = c0 + (sid & 7) + ((sid >> 3) << 10); }
    else if (sid < 32) { int s = sid - 16; mat = 1; gcol = c0 + (s & 7) + ((s >> 3) << 10); }
    else if (sid < 56) { int s = sid - 32; mat = 2; gcol = c0 + (s & 7) + ((s >> 3) << 10); }
    else               { int s = sid - 56; mat = (s < 8) ? 0 : 1; gcol = 2 * U + c0 + (s & 7); }
    bf16x8 v = *(const bf16x8*)(WT + ((size_t)mat * U3 + gcol) * U + chunk * 8);
    *(bf16x8*)(Wlds + ((size_t)sid << 10) + ((chunk ^ (sid & 7) ^ (sid & 8)) << 3)) = v;
  }
  __syncthreads();

  // ---- per-lane biases ----
  const int zr_idx = (lr < 8) ? (c0 + lr) : (U + c0 + lr - 8);
  const int n_idx = 2 * U + c0 + (lr & 7);
  const float bzr1 = bh1[zr_idx];
  const float bhn1 = bh1[n_idx];
  const float bzr2 = bx2[zr_idx] + bh2[zr_idx];
  const float bxn2 = bx2[n_idx];
  const float bhn2 = bh2[n_idx];

  float hm[4];                                // fp32 master state slice (role-owned)
  #pragma unroll
  for (int q = 0; q < 4; ++q) hm[q] = 0.f;

  for (int i = 0; i <= T_SEQ; ++i) {
    // deep buffers: iter i reads h0b[i], h1b[i-1]; writes h0b[i+1], h1b[i].
    const bf16* h0r = h0b + (size_t)i * HBUF_ELEMS;
    const bf16* h1r = h1b + (size_t)(i > 0 ? i - 1 : 0) * HBUF_ELEMS;
    bf16* h0w = h0b + (size_t)(i + 1) * HBUF_ELEMS;
    bf16* h1w = h1b + (size_t)i * HBUF_ELEMS;

    f32x4 a3zr = {}, a3n = {};

    if (w < 8) {
      // ===== h0-waves: gh1-zr + gx2-zr + combined-n (shared A = H0[i-1]) =====
      f32x4 a1zr = {}, a2zr = {}, an = {};

      // hoist GX1 gate loads (precomputed, barrier-independent)
      bf16x4 g4p = {}, gnp = {};
      if (i < T_SEQ) {
        const bf16* gx = GX1 + (size_t)i * U3 * 128;
        int r0 = w * 16 + lq * 4;
        g4p = *(const bf16x4*)(gx + (size_t)zr_idx * 128 + r0);
        gnp = *(const bf16x4*)(gx + (size_t)(2 * U + c0 + (lr & 7)) * 128 + r0);
      }

      const bf16* abase = h0r + (size_t)(w * 16 + lr) * U + lq * 8;
      #pragma unroll 8
      for (int ks = 0; ks < 32; ++ks) {
        int kss = (ks + koff) & 31;            // staggered K-walk
        bf16x8 A = *(const bf16x8*)(abase + kss * 32);
        int k8 = kss * 4 + lq;
        bf16x8 B1zr = ldsw(Wlds, lr, k8);
        bf16x8 B2zr = ldsw(Wlds, 16 + lr, k8);
        bf16x8 Bn   = ldsw(Wlds, 56 + lr, k8);   // lr<8: Wh1-n, lr>=8: Wx2-n
        a1zr = __builtin_amdgcn_mfma_f32_16x16x32_bf16(A, B1zr, a1zr, 0, 0, 0);
        a2zr = __builtin_amdgcn_mfma_f32_16x16x32_bf16(A, B2zr, a2zr, 0, 0, 0);
        an   = __builtin_amdgcn_mfma_f32_16x16x32_bf16(A, Bn,   an,   0, 0, 0);
      }
      // deposit gx2 for the h1-waves: zr from all lanes, n from lanes lr>=8
      {
        int r0 = w * 16 + lq * 4;
        *(f32x4*)(Sx2 + lr * 132 + r0) = a2zr;
        if (lr >= 8) *(f32x4*)(Sx2 + (16 + (lr - 8)) * 132 + r0) = an;
      }
      // h0 update: H0[i] = GRU1(H0[i-1], x[i])
      if (i < T_SEQ) {
        int r0 = w * 16 + lq * 4;
        f32x4 sv;
        #pragma unroll
        for (int j = 0; j < 4; ++j) sv[j] = sigmoidf_(a1zr[j] + bzr1 + (float)g4p[j]);
        f32x4 rv;
        #pragma unroll
        for (int j = 0; j < 4; ++j) rv[j] = __shfl_xor(sv[j], 8);
        if (lr < 8) {
          #pragma unroll
          for (int j = 0; j < 4; ++j) {
            float nn = tanhf((float)gnp[j] + rv[j] * (an[j] + bhn1));
            float z = sv[j];
            float h = z * hm[j] + (1.f - z) * nn;
            hm[j] = h;
            st_pair(h0w + (size_t)(r0 + j) * U + c0 + (lr & ~1), lr, h);
          }
        }
      }
    } else if (i > 0) {
      // ===== h1-waves: gh2 = H1[i-2]@Wh2 =====
      const bf16* abase = h1r + (size_t)((w - 8) * 16 + lr) * U + lq * 8;
      #pragma unroll 8
      for (int ks = 0; ks < 32; ++ks) {
        int kss = (ks + koff) & 31;
        bf16x8 A = *(const bf16x8*)(abase + kss * 32);
        int k8 = kss * 4 + lq;
        bf16x8 B3zr = ldsw(Wlds, 32 + lr, k8);
        bf16x8 B3n  = ldsw(Wlds, 48 + (lr & 7), k8);
        a3zr = __builtin_amdgcn_mfma_f32_16x16x32_bf16(A, B3zr, a3zr, 0, 0, 0);
        a3n  = __builtin_amdgcn_mfma_f32_16x16x32_bf16(A, B3n,  a3n, 0, 0, 0);
      }
    }
    __syncthreads();   // gx2 handoff visible to h1-waves
    if (w >= 8 && i > 0) {
      // h1 update: H1[i-1] = GRU2(H1[i-2], H0[i-1])
      int r0 = (w - 8) * 16 + lq * 4;
      f32x4 sv;
      #pragma unroll
      for (int j = 0; j < 4; ++j)
        sv[j] = sigmoidf_(a3zr[j] + bzr2 + Sx2[lr * 132 + r0 + j]);
      f32x4 rv;
      #pragma unroll
      for (int j = 0; j < 4; ++j) rv[j] = __shfl_xor(sv[j], 8);
      if (lr < 8) {
        #pragma unroll
        for (int j = 0; j < 4; ++j) {
          float xn = Sx2[(16 + lr) * 132 + r0 + j] + bxn2;
          float nn = tanhf(xn + rv[j] * (a3n[j] + bhn2));
          float z = sv[j];
          float h = z * hm[j] + (1.f - z) * nn;
          hm[j] = h;
          st_pair(h1w + (size_t)(r0 + j) * U + c0 + (lr & ~1), lr, h);
        }
      }
    }
    gridbar(cnt, i);
  }

  // ---- final dense head: out[b] = sigmoid(H1[79] . Wf + bf), block b ----
  {
    const bf16* h1f = h1b + (size_t)T_SEQ * HBUF_ELEMS + (size_t)blockIdx.x * U;
    float part = 0.f;
    if (tid < 256) {
      int k0 = tid * 4;
      bf16x4 hv = *(const bf16x4*)(h1f + k0);
      #pragma unroll
      for (int j = 0; j < 4; ++j) part += (float)hv[j] * Wf[k0 + j];
    }
    #pragma unroll
    for (int off = 32; off > 0; off >>= 1) part += __shfl_down(part, off);
    if (l == 0) red[w] = part;
    __syncthreads();
    if (tid == 0) {
      float s = bfp[0];
      #pragma unroll
      for (int q = 0; q < 16; ++q) s += red[q];
      out[blockIdx.x] = sigmoidf_(s);
    }
  }
}

extern "C" void kernel_launch(void* const* d_in, const int* in_sizes, int n_in,
                              void* d_out, int out_size, void* d_ws, size_t ws_size,
                              hipStream_t stream) {
  if (ws_size < WS_NEED) return;  // workspace insufficient -> deliberate clean fail
  const int*   tok = (const int*)d_in[0];
  const float* E   = (const float*)d_in[1];
  const float* Wx1 = (const float*)d_in[2];
  const float* Wh1 = (const float*)d_in[3];
  const float* bx1 = (const float*)d_in[4];
  const float* bh1 = (const float*)d_in[5];
  const float* Wx2 = (const float*)d_in[6];
  const float* Wh2 = (const float*)d_in[7];
  const float* bx2 = (const float*)d_in[8];
  const float* bh2 = (const float*)d_in[9];
  const float* Wf  = (const float*)d_in[10];
  const float* bfp = (const float*)d_in[11];
  char* ws = (char*)d_ws;
  bf16* WT   = (bf16*)(ws + WT_OFF);
  bf16* WXT  = (bf16*)(ws + WXT_OFF);
  bf16* Xg   = (bf16*)(ws + XG_OFF);
  bf16* GX1  = (bf16*)(ws + GX1_OFF);
  bf16* h0b  = (bf16*)(ws + H0B_OFF);
  bf16* h1b  = (bf16*)(ws + H1B_OFF);
  int*  cnt  = (int*)(ws + CNT_OFF);

  // zero only what's read-before-write: h0b[0], h1b[0], counters
  hipMemsetAsync(ws + H0B_OFF, 0, 262144, stream);
  hipMemsetAsync(ws + H1B_OFF, 0, 262144, stream);
  hipMemsetAsync(ws + CNT_OFF, 0, 2048, stream);
  k_embed<<<dim3(5120), dim3(256), 0, stream>>>(tok, E, Xg);
  k_trans<<<dim3(96, 32, 3), dim3(32, 8), 0, stream>>>(Wh1, Wx2, Wh2, WT);
  k_wxt<<<dim3(96, 4), dim3(32, 8), 0, stream>>>(Wx1, WXT);
  k_gx1<<<dim3(160, 48), dim3(256), 0, stream>>>(Xg, WXT, bx1, GX1);
  hipFuncSetAttribute((const void*)k_main, hipFuncAttributeMaxDynamicSharedMemorySize, LDS_BYTES);
  k_main<<<dim3(NB), dim3(NT), LDS_BYTES, stream>>>(WT, GX1, h0b, h1b, cnt,
                                                    bh1, bx2, bh2, Wf, bfp, (float*)d_out);
}

// Round 15
// 1542.194 us; speedup vs baseline: 1.6592x; 1.0005x over previous
//
#include <hip/hip_runtime.h>
#include <hip/hip_bf16.h>

typedef __bf16 bf16;
typedef __bf16 bf16x8 __attribute__((ext_vector_type(8)));
typedef __bf16 bf16x4 __attribute__((ext_vector_type(4)));
typedef float f32x4 __attribute__((ext_vector_type(4)));

#define T_SEQ 80
#define NB 128
#define NT 1024
#define U 1024
#define U3 3072

// ws byte offsets
#define WT_OFF   0ull                  // 3*3072*1024*2 = 18874368
#define WXT_OFF  18874368ull           // 3072*128*2    = 786432
#define XG_OFF   19660800ull           // 80*128*128*2  = 2621440
#define GX1_OFF  22282240ull           // 80*3072*128*2 = 62914560
#define H0B_OFF  85196800ull           // 81 * 128*1024*2 = 21233664 (deep buffers)
#define H1B_OFF  106430464ull          // 21233664
#define CNT_OFF  127664128ull          // barrier counters (2048 B)
#define WS_NEED  127666176ull

#define HBUF_ELEMS 131072ull           // 128*1024 bf16 per h buffer

#define LDS_SX2_OFF   147456                  // after 72*1024 bf16 weight slots
#define LDS_RED_OFF   (147456 + 24*132*4)     // after Sx2[24][132] f32
#define LDS_BYTES     (LDS_RED_OFF + 64)      // = 160192 <= 163840

__device__ __forceinline__ float sigmoidf_(float x) { return 1.f / (1.f + __expf(-x)); }

__global__ void k_embed(const int* __restrict__ tok, const float* __restrict__ E,
                        bf16* __restrict__ Xg) {
  int idx = blockIdx.x * 256 + threadIdx.x;   // over 80*128*128, layout [t][b][k]
  int k = idx & 127;
  int bt = idx >> 7;
  int b = bt & 127;
  int t = bt >> 7;
  float v = 0.f;
  if (k < 100) v = E[(size_t)tok[b * 80 + t] * 100 + k];
  Xg[idx] = (bf16)v;
}

__global__ void k_trans(const float* __restrict__ Wh1, const float* __restrict__ Wx2,
                        const float* __restrict__ Wh2, bf16* __restrict__ WT) {
  __shared__ float tile[32][33];
  const float* src = (blockIdx.z == 0) ? Wh1 : (blockIdx.z == 1) ? Wx2 : Wh2;
  int cb = blockIdx.x * 32, kb = blockIdx.y * 32;
  int tx = threadIdx.x, ty = threadIdx.y;
  for (int i = ty; i < 32; i += 8) tile[i][tx] = src[(size_t)(kb + i) * U3 + cb + tx];
  __syncthreads();
  bf16* dst = WT + (size_t)blockIdx.z * U3 * U;  // [col][k] bf16
  for (int i = ty; i < 32; i += 8) dst[(size_t)(cb + i) * U + kb + tx] = (bf16)tile[tx][i];
}

__global__ void k_wxt(const float* __restrict__ Wx1, bf16* __restrict__ WXT) {
  __shared__ float tile[32][33];
  int cb = blockIdx.x * 32, kb = blockIdx.y * 32;
  int tx = threadIdx.x, ty = threadIdx.y;
  for (int i = ty; i < 32; i += 8) {
    int k = kb + i;
    tile[i][tx] = (k < 100) ? Wx1[(size_t)k * U3 + cb + tx] : 0.f;
  }
  __syncthreads();
  for (int i = ty; i < 32; i += 8) WXT[(size_t)(cb + i) * 128 + kb + tx] = (bf16)tile[tx][i];
}

// GX1[t][col][b] = (x_t @ Wx1 + bx1), bf16, col-major over batch
__global__ __launch_bounds__(256) void k_gx1(const bf16* __restrict__ Xg,
                                             const bf16* __restrict__ WXT,
                                             const float* __restrict__ bx1,
                                             bf16* __restrict__ GX1) {
  int mb = blockIdx.x * 64, nb = blockIdx.y * 64;
  int w = threadIdx.x >> 6, l = threadIdx.x & 63;
  int lr = l & 15, lq = l >> 4;
  int rowA = mb + w * 16 + lr;                 // m = t*128 + b
  int tA = rowA >> 7, bA = rowA & 127;
  const bf16* aptr = Xg + ((size_t)tA * 128 + bA) * 128 + lq * 8;
  f32x4 acc[4] = {};
  #pragma unroll
  for (int ks = 0; ks < 4; ++ks) {
    bf16x8 a = *(const bf16x8*)(aptr + ks * 32);
    #pragma unroll
    for (int nt = 0; nt < 4; ++nt) {
      int col = nb + nt * 16 + lr;
      bf16x8 b = *(const bf16x8*)(WXT + (size_t)col * 128 + ks * 32 + lq * 8);
      acc[nt] = __builtin_amdgcn_mfma_f32_16x16x32_bf16(a, b, acc[nt], 0, 0, 0);
    }
  }
  int m0 = mb + w * 16 + lq * 4;
  int t0 = m0 >> 7, b0 = m0 & 127;
  #pragma unroll
  for (int nt = 0; nt < 4; ++nt) {
    int col = nb + nt * 16 + lr;
    float bias = bx1[col];
    bf16x4 o;
    #pragma unroll
    for (int j = 0; j < 4; ++j) o[j] = (bf16)(acc[nt][j] + bias);
    *(bf16x4*)(GX1 + ((size_t)t0 * U3 + col) * 128 + b0) = o;
  }
}

// Weight slot layout (72 slots x 1024 bf16, 16B-granule XOR-swizzled):
//   sid  0-15: Wh1 z(0-7) r(8-15)
//   sid 16-31: Wx2 z(0-7) r(8-15)
//   sid 32-55: Wh2 z(0-7) r(8-15) n(16-23)
//   sid 56-71: combined n: 56-63 = Wh1 n-cols, 64-71 = Wx2 n-cols
__device__ __forceinline__ bf16x8 ldsw(const bf16* Wlds, int sid, int k8) {
  return *(const bf16x8*)(Wlds + ((size_t)sid << 10) + ((k8 ^ (sid & 7) ^ (sid & 8)) << 3));
}

// Packed-pair h store: lanes lr (even) and lr+1 hold adjacent columns, same row.
// Agent-scope relaxed atomic store -> data lands at the coherence point (IF).
__device__ __forceinline__ void st_pair(bf16* dst_even, int lr, float h) {
  bf16 hb16 = (bf16)h;
  unsigned hb = (unsigned)__builtin_bit_cast(unsigned short, hb16);
  unsigned pb = (unsigned)__shfl_xor((int)hb, 1) & 0xffffu;
  if (!(lr & 1)) {
    unsigned v = hb | (pb << 16);
    __hip_atomic_store((unsigned*)dst_even, v, __ATOMIC_RELAXED, __HIP_MEMORY_SCOPE_AGENT);
  }
}

// Fence-free tree barrier (measured ~1.67 us/barrier at 128 blocks).
__device__ void gridbar(int* cnt, int i) {
  __syncthreads();
  if (threadIdx.x == 0) {
    int* gc   = cnt + (blockIdx.x & 7) * 32;   // 128B apart
    int* root = cnt + 256;
    int* go   = cnt + 288;
    int old = __hip_atomic_fetch_add(gc, 1, __ATOMIC_RELAXED, __HIP_MEMORY_SCOPE_AGENT);
    if (old == 16 * (i + 1) - 1) {             // group leader this iteration
      int r = __hip_atomic_fetch_add(root, 1, __ATOMIC_RELAXED, __HIP_MEMORY_SCOPE_AGENT);
      if (r == 8 * (i + 1) - 1)
        __hip_atomic_store(go, i + 1, __ATOMIC_RELAXED, __HIP_MEMORY_SCOPE_AGENT);
    }
    while (__hip_atomic_load(go, __ATOMIC_RELAXED, __HIP_MEMORY_SCOPE_AGENT) < i + 1)
      __builtin_amdgcn_s_sleep(4);
  }
  __syncthreads();
}

// NT=1024: waves 0-7 = h0 (gh1 + gx2 + combined-n, 16 rows each), waves 8-15 = h1.
// 4 waves/SIMD; 32-step shared-A chains (r9 skeleton, validated best).
__global__ __launch_bounds__(NT, 1) void k_main(
    const bf16* __restrict__ WT, const bf16* __restrict__ GX1,
    bf16* __restrict__ h0b, bf16* __restrict__ h1b, int* __restrict__ cnt,
    const float* __restrict__ bh1, const float* __restrict__ bx2,
    const float* __restrict__ bh2, const float* __restrict__ Wf,
    const float* __restrict__ bfp, float* __restrict__ out) {
  extern __shared__ char lds[];
  bf16* Wlds = (bf16*)lds;
  float* Sx2 = (float*)(lds + LDS_SX2_OFF);   // [24][132] f32: gx2 handoff
  float* red = (float*)(lds + LDS_RED_OFF);   // 16 floats

  const int tid = threadIdx.x;
  const int w = tid >> 6, l = tid & 63;
  const int lr = l & 15, lq = l >> 4;
  const int c0 = blockIdx.x * 8;              // this block's h-column base
  // XCD-LOCAL K-walk stagger: blocks land on XCDs round-robin (blockIdx%8), so
  // (blockIdx>>3)&15 enumerates the 16 blocks sharing one XCD's L2. Staggering
  // their K-walk start (stride 2 granules = 64 elems) makes them request
  // DIFFERENT lines at any instant: 1 fills from IF, 15 hit L2 (not MSHR-merge).
  const int koff = ((blockIdx.x >> 3) & 15) * 2;

  // ---- stage 72 weight slots into LDS (bf16, k-contiguous, XOR-swizzled) ----
  for (int u = tid; u < 9216; u += NT) {      // 72 slots * 128 granules
    int chunk = u & 127;
    int sid = u >> 7;
    int mat, gcol;
    if (sid < 16)      { mat = 0; gcol = c0 + (sid & 7) + ((sid >> 3) << 10); }
    else if (sid < 32) { int s = sid - 16; mat = 1; gcol = c0 + (s & 7) + ((s >> 3) << 10); }
    else if (sid < 56) { int s = sid - 32; mat = 2; gcol = c0 + (s & 7) + ((s >> 3) << 10); }
    else               { int s = sid - 56; mat = (s < 8) ? 0 : 1; gcol = 2 * U + c0 + (s & 7); }
    bf16x8 v = *(const bf16x8*)(WT + ((size_t)mat * U3 + gcol) * U + chunk * 8);
    *(bf16x8*)(Wlds + ((size_t)sid << 10) + ((chunk ^ (sid & 7) ^ (sid & 8)) << 3)) = v;
  }
  __syncthreads();

  // ---- per-lane biases ----
  const int zr_idx = (lr < 8) ? (c0 + lr) : (U + c0 + lr - 8);
  const int n_idx = 2 * U + c0 + (lr & 7);
  const float bzr1 = bh1[zr_idx];
  const float bhn1 = bh1[n_idx];
  const float bzr2 = bx2[zr_idx] + bh2[zr_idx];
  const float bxn2 = bx2[n_idx];
  const float bhn2 = bh2[n_idx];

  float hm[4];                                // fp32 master state slice (role-owned)
  #pragma unroll
  for (int q = 0; q < 4; ++q) hm[q] = 0.f;

  for (int i = 0; i <= T_SEQ; ++i) {
    // deep buffers: iter i reads h0b[i], h1b[i-1]; writes h0b[i+1], h1b[i].
    const bf16* h0r = h0b + (size_t)i * HBUF_ELEMS;
    const bf16* h1r = h1b + (size_t)(i > 0 ? i - 1 : 0) * HBUF_ELEMS;
    bf16* h0w = h0b + (size_t)(i + 1) * HBUF_ELEMS;
    bf16* h1w = h1b + (size_t)i * HBUF_ELEMS;

    f32x4 a3zr = {}, a3n = {};

    if (w < 8) {
      // ===== h0-waves: gh1-zr + gx2-zr + combined-n (shared A = H0[i-1]) =====
      f32x4 a1zr = {}, a2zr = {}, an = {};

      // hoist GX1 gate loads (precomputed, barrier-independent)
      bf16x4 g4p = {}, gnp = {};
      if (i < T_SEQ) {
        const bf16* gx = GX1 + (size_t)i * U3 * 128;
        int r0 = w * 16 + lq * 4;
        g4p = *(const bf16x4*)(gx + (size_t)zr_idx * 128 + r0);
        gnp = *(const bf16x4*)(gx + (size_t)(2 * U + c0 + (lr & 7)) * 128 + r0);
      }

      const bf16* abase = h0r + (size_t)(w * 16 + lr) * U + lq * 8;
      #pragma unroll 8
      for (int ks = 0; ks < 32; ++ks) {
        int kss = (ks + koff) & 31;            // XCD-local staggered K-walk
        bf16x8 A = *(const bf16x8*)(abase + kss * 32);
        int k8 = kss * 4 + lq;
        bf16x8 B1zr = ldsw(Wlds, lr, k8);
        bf16x8 B2zr = ldsw(Wlds, 16 + lr, k8);
        bf16x8 Bn   = ldsw(Wlds, 56 + lr, k8);   // lr<8: Wh1-n, lr>=8: Wx2-n
        a1zr = __builtin_amdgcn_mfma_f32_16x16x32_bf16(A, B1zr, a1zr, 0, 0, 0);
        a2zr = __builtin_amdgcn_mfma_f32_16x16x32_bf16(A, B2zr, a2zr, 0, 0, 0);
        an   = __builtin_amdgcn_mfma_f32_16x16x32_bf16(A, Bn,   an,   0, 0, 0);
      }
      // deposit gx2 for the h1-waves: zr from all lanes, n from lanes lr>=8
      {
        int r0 = w * 16 + lq * 4;
        *(f32x4*)(Sx2 + lr * 132 + r0) = a2zr;
        if (lr >= 8) *(f32x4*)(Sx2 + (16 + (lr - 8)) * 132 + r0) = an;
      }
      // h0 update: H0[i] = GRU1(H0[i-1], x[i])
      if (i < T_SEQ) {
        int r0 = w * 16 + lq * 4;
        f32x4 sv;
        #pragma unroll
        for (int j = 0; j < 4; ++j) sv[j] = sigmoidf_(a1zr[j] + bzr1 + (float)g4p[j]);
        f32x4 rv;
        #pragma unroll
        for (int j = 0; j < 4; ++j) rv[j] = __shfl_xor(sv[j], 8);
        if (lr < 8) {
          #pragma unroll
          for (int j = 0; j < 4; ++j) {
            float nn = tanhf((float)gnp[j] + rv[j] * (an[j] + bhn1));
            float z = sv[j];
            float h = z * hm[j] + (1.f - z) * nn;
            hm[j] = h;
            st_pair(h0w + (size_t)(r0 + j) * U + c0 + (lr & ~1), lr, h);
          }
        }
      }
    } else if (i > 0) {
      // ===== h1-waves: gh2 = H1[i-2]@Wh2 =====
      const bf16* abase = h1r + (size_t)((w - 8) * 16 + lr) * U + lq * 8;
      #pragma unroll 8
      for (int ks = 0; ks < 32; ++ks) {
        int kss = (ks + koff) & 31;
        bf16x8 A = *(const bf16x8*)(abase + kss * 32);
        int k8 = kss * 4 + lq;
        bf16x8 B3zr = ldsw(Wlds, 32 + lr, k8);
        bf16x8 B3n  = ldsw(Wlds, 48 + (lr & 7), k8);
        a3zr = __builtin_amdgcn_mfma_f32_16x16x32_bf16(A, B3zr, a3zr, 0, 0, 0);
        a3n  = __builtin_amdgcn_mfma_f32_16x16x32_bf16(A, B3n,  a3n, 0, 0, 0);
      }
    }
    __syncthreads();   // gx2 handoff visible to h1-waves
    if (w >= 8 && i > 0) {
      // h1 update: H1[i-1] = GRU2(H1[i-2], H0[i-1])
      int r0 = (w - 8) * 16 + lq * 4;
      f32x4 sv;
      #pragma unroll
      for (int j = 0; j < 4; ++j)
        sv[j] = sigmoidf_(a3zr[j] + bzr2 + Sx2[lr * 132 + r0 + j]);
      f32x4 rv;
      #pragma unroll
      for (int j = 0; j < 4; ++j) rv[j] = __shfl_xor(sv[j], 8);
      if (lr < 8) {
        #pragma unroll
        for (int j = 0; j < 4; ++j) {
          float xn = Sx2[(16 + lr) * 132 + r0 + j] + bxn2;
          float nn = tanhf(xn + rv[j] * (a3n[j] + bhn2));
          float z = sv[j];
          float h = z * hm[j] + (1.f - z) * nn;
          hm[j] = h;
          st_pair(h1w + (size_t)(r0 + j) * U + c0 + (lr & ~1), lr, h);
        }
      }
    }
    gridbar(cnt, i);
  }

  // ---- final dense head: out[b] = sigmoid(H1[79] . Wf + bf), block b ----
  {
    const bf16* h1f = h1b + (size_t)T_SEQ * HBUF_ELEMS + (size_t)blockIdx.x * U;
    float part = 0.f;
    if (tid < 256) {
      int k0 = tid * 4;
      bf16x4 hv = *(const bf16x4*)(h1f + k0);
      #pragma unroll
      for (int j = 0; j < 4; ++j) part += (float)hv[j] * Wf[k0 + j];
    }
    #pragma unroll
    for (int off = 32; off > 0; off >>= 1) part += __shfl_down(part, off);
    if (l == 0) red[w] = part;
    __syncthreads();
    if (tid == 0) {
      float s = bfp[0];
      #pragma unroll
      for (int q = 0; q < 16; ++q) s += red[q];
      out[blockIdx.x] = sigmoidf_(s);
    }
  }
}

extern "C" void kernel_launch(void* const* d_in, const int* in_sizes, int n_in,
                              void* d_out, int out_size, void* d_ws, size_t ws_size,
                              hipStream_t stream) {
  if (ws_size < WS_NEED) return;  // workspace insufficient -> deliberate clean fail
  const int*   tok = (const int*)d_in[0];
  const float* E   = (const float*)d_in[1];
  const float* Wx1 = (const float*)d_in[2];
  const float* Wh1 = (const float*)d_in[3];
  const float* bx1 = (const float*)d_in[4];
  const float* bh1 = (const float*)d_in[5];
  const float* Wx2 = (const float*)d_in[6];
  const float* Wh2 = (const float*)d_in[7];
  const float* bx2 = (const float*)d_in[8];
  const float* bh2 = (const float*)d_in[9];
  const float* Wf  = (const float*)d_in[10];
  const float* bfp = (const float*)d_in[11];
  char* ws = (char*)d_ws;
  bf16* WT   = (bf16*)(ws + WT_OFF);
  bf16* WXT  = (bf16*)(ws + WXT_OFF);
  bf16* Xg   = (bf16*)(ws + XG_OFF);
  bf16* GX1  = (bf16*)(ws + GX1_OFF);
  bf16* h0b  = (bf16*)(ws + H0B_OFF);
  bf16* h1b  = (bf16*)(ws + H1B_OFF);
  int*  cnt  = (int*)(ws + CNT_OFF);

  // zero only what's read-before-write: h0b[0], h1b[0], counters
  hipMemsetAsync(ws + H0B_OFF, 0, 262144, stream);
  hipMemsetAsync(ws + H1B_OFF, 0, 262144, stream);
  hipMemsetAsync(ws + CNT_OFF, 0, 2048, stream);
  k_embed<<<dim3(5120), dim3(256), 0, stream>>>(tok, E, Xg);
  k_trans<<<dim3(96, 32, 3), dim3(32, 8), 0, stream>>>(Wh1, Wx2, Wh2, WT);
  k_wxt<<<dim3(96, 4), dim3(32, 8), 0, stream>>>(Wx1, WXT);
  k_gx1<<<dim3(160, 48), dim3(256), 0, stream>>>(Xg, WXT, bx1, GX1);
  hipFuncSetAttribute((const void*)k_main, hipFuncAttributeMaxDynamicSharedMemorySize, LDS_BYTES);
  k_main<<<dim3(NB), dim3(NT), LDS_BYTES, stream>>>(WT, GX1, h0b, h1b, cnt,
                                                    bh1, bx2, bh2, Wf, bfp, (float*)d_out);
}